// Round 3
// baseline (23174.510 us; speedup 1.0000x reference)
//
#include <hip/hip_runtime.h>
#include <cstddef>

// Problem constants: H=512 B=512 S=128 T=64 V=29 SOS=27 TF_RATIO=0.6
// Outputs (floats, concat): vec_out (512,64,29)=950272 | hn (2,512,512)=524288 | attn_last (512,1,128)=65536

static __device__ __forceinline__ float sigf(float x) { return 1.0f / (1.0f + expf(-x)); }
static __device__ __forceinline__ unsigned rotl32(unsigned x, int r) { return (x << r) | (x >> (32 - r)); }

// ---------------- init: tok=SOS, tf_mask = jax.random.uniform(key(42),(64,)) < 0.6 ----------------
// PARTITIONABLE threefry (modern JAX default, jax_threefry_partitionable=True):
// element i uses 64-bit counter i -> words (hi=0, lo=i); 32-bit bits = y0 ^ y1.
__global__ __launch_bounds__(512) void init_kernel(int* __restrict__ tok, int* __restrict__ tfm) {
  int t = threadIdx.x;
  if (t < 64) {
    unsigned ks[3] = {0u, 42u, 0u ^ 42u ^ 0x1BD11BDAu};
    unsigned x0 = 0u + ks[0];              // count_hi = 0
    unsigned x1 = (unsigned)t + ks[1];     // count_lo = i
    const int RA[4] = {13, 15, 26, 6};
    const int RB[4] = {17, 29, 16, 24};
    #pragma unroll
    for (int g = 0; g < 5; ++g) {
      #pragma unroll
      for (int r = 0; r < 4; ++r) {
        int rot = (g & 1) ? RB[r] : RA[r];
        x0 += x1; x1 = rotl32(x1, rot); x1 ^= x0;
      }
      x0 += ks[(g + 1) % 3];
      x1 += ks[(g + 2) % 3] + (unsigned)(g + 1);
    }
    unsigned bits = x0 ^ x1;               // fold 64->32 (partitionable, bit_width<64)
    float u = __uint_as_float((bits >> 9) | 0x3f800000u) - 1.0f;
    tfm[t] = (u < 0.6f) ? 1 : 0;
  }
  tok[t] = 27;  // SOS
}

// ---------------- embW = emb @ dec0_Wih.T : (29 x 2048), one-off, fp64-accurate ----------------
__global__ __launch_bounds__(256) void embw_kernel(const float* __restrict__ emb,
                                                   const float* __restrict__ Wih,
                                                   float* __restrict__ embW) {
  int v = blockIdx.x;                        // 0..28
  int n = blockIdx.y * 256 + threadIdx.x;    // 0..2047
  const float4* er = (const float4*)(emb + (size_t)v * 512);
  const float4* wr = (const float4*)(Wih + (size_t)n * 512);
  double acc = 0.0;
  #pragma unroll 4
  for (int k = 0; k < 128; ++k) {
    float4 a = er[k], w = wr[k];
    acc += (double)a.x * w.x + (double)a.y * w.y + (double)a.z * w.z + (double)a.w * w.w;
  }
  embW[(size_t)v * 2048 + n] = (float)acc;
}

// ---------------- fused LSTM cell: g = X@Wih.T + Hin@Whh.T + b; LSTM update ----------------
// Block computes 64 b x 16 hu x 4 gates. mode 0: Kx=2 (enc0, xstride=256)
// mode 1: Kx=512 dense X. mode 2: X-part = embW[tok[b]] gather (dec0).
// fp32 FMA within 16-wide K-chunks, chunks folded into fp64 (keeps the recurrent
// trajectory at ~exact-sum accuracy so decoder argmax(h1) decisions match ref).
__global__ __launch_bounds__(256) void cell_kernel(
    const float* __restrict__ X, int xstride,
    const int* __restrict__ tok, const float* __restrict__ embW,
    const float* __restrict__ Hin, float* __restrict__ Cio, float* __restrict__ Hout,
    const float* __restrict__ Wih, const float* __restrict__ Whh,
    const float* __restrict__ bias, int mode)
{
  __shared__ float As[16][64];
  __shared__ float Ws[16][64];
  const int t   = threadIdx.x;
  const int tb  = t >> 4;            // 0..15 (b group of 4)
  const int th  = t & 15;            // 0..15 (hu)
  const int b0  = blockIdx.x * 64;
  const int hu0 = blockIdx.y * 16;
  const int nl  = t >> 2;            // 0..63 staging row
  const int kk4 = (t & 3) * 4;
  const int wrow = (nl & 3) * 512 + hu0 + (nl >> 2);  // gate*512 + hu

  double accd[4][4] = {{0.0}};

  if (mode == 0) {
    #pragma unroll
    for (int i = 0; i < 4; ++i) {
      int b = b0 + tb * 4 + i;
      float xv0 = X[(size_t)b * xstride];
      float xv1 = X[(size_t)b * xstride + 1];
      #pragma unroll
      for (int g = 0; g < 4; ++g) {
        int n = g * 512 + hu0 + th;
        accd[i][g] += (double)xv0 * Wih[n * 2] + (double)xv1 * Wih[n * 2 + 1];
      }
    }
  } else if (mode == 2) {
    #pragma unroll
    for (int i = 0; i < 4; ++i) {
      int b = b0 + tb * 4 + i;
      const float* er = embW + (size_t)tok[b] * 2048;
      #pragma unroll
      for (int g = 0; g < 4; ++g)
        accd[i][g] += (double)er[g * 512 + hu0 + th];
    }
  } else {
    const float* Arow = X + (size_t)(b0 + nl) * xstride + kk4;
    const float* Wr   = Wih + (size_t)wrow * 512 + kk4;
    for (int k0 = 0; k0 < 512; k0 += 16) {
      float4 av = *(const float4*)(Arow + k0);
      float4 wv = *(const float4*)(Wr + k0);
      As[kk4 + 0][nl] = av.x; As[kk4 + 1][nl] = av.y; As[kk4 + 2][nl] = av.z; As[kk4 + 3][nl] = av.w;
      Ws[kk4 + 0][nl] = wv.x; Ws[kk4 + 1][nl] = wv.y; Ws[kk4 + 2][nl] = wv.z; Ws[kk4 + 3][nl] = wv.w;
      __syncthreads();
      float acc[4][4] = {{0.f}};
      #pragma unroll
      for (int kk = 0; kk < 16; ++kk) {
        float4 a = *(const float4*)&As[kk][tb * 4];
        float4 w = *(const float4*)&Ws[kk][th * 4];
        acc[0][0] += a.x * w.x; acc[0][1] += a.x * w.y; acc[0][2] += a.x * w.z; acc[0][3] += a.x * w.w;
        acc[1][0] += a.y * w.x; acc[1][1] += a.y * w.y; acc[1][2] += a.y * w.z; acc[1][3] += a.y * w.w;
        acc[2][0] += a.z * w.x; acc[2][1] += a.z * w.y; acc[2][2] += a.z * w.z; acc[2][3] += a.z * w.w;
        acc[3][0] += a.w * w.x; acc[3][1] += a.w * w.y; acc[3][2] += a.w * w.z; acc[3][3] += a.w * w.w;
      }
      #pragma unroll
      for (int i = 0; i < 4; ++i)
        #pragma unroll
        for (int g = 0; g < 4; ++g)
          accd[i][g] += (double)acc[i][g];
      __syncthreads();
    }
  }

  // hidden-state part, K=512, always
  {
    const float* Arow = Hin + (size_t)(b0 + nl) * 512 + kk4;
    const float* Wr   = Whh + (size_t)wrow * 512 + kk4;
    for (int k0 = 0; k0 < 512; k0 += 16) {
      float4 av = *(const float4*)(Arow + k0);
      float4 wv = *(const float4*)(Wr + k0);
      As[kk4 + 0][nl] = av.x; As[kk4 + 1][nl] = av.y; As[kk4 + 2][nl] = av.z; As[kk4 + 3][nl] = av.w;
      Ws[kk4 + 0][nl] = wv.x; Ws[kk4 + 1][nl] = wv.y; Ws[kk4 + 2][nl] = wv.z; Ws[kk4 + 3][nl] = wv.w;
      __syncthreads();
      float acc[4][4] = {{0.f}};
      #pragma unroll
      for (int kk = 0; kk < 16; ++kk) {
        float4 a = *(const float4*)&As[kk][tb * 4];
        float4 w = *(const float4*)&Ws[kk][th * 4];
        acc[0][0] += a.x * w.x; acc[0][1] += a.x * w.y; acc[0][2] += a.x * w.z; acc[0][3] += a.x * w.w;
        acc[1][0] += a.y * w.x; acc[1][1] += a.y * w.y; acc[1][2] += a.y * w.z; acc[1][3] += a.y * w.w;
        acc[2][0] += a.z * w.x; acc[2][1] += a.z * w.y; acc[2][2] += a.z * w.z; acc[2][3] += a.z * w.w;
        acc[3][0] += a.w * w.x; acc[3][1] += a.w * w.y; acc[3][2] += a.w * w.z; acc[3][3] += a.w * w.w;
      }
      #pragma unroll
      for (int i = 0; i < 4; ++i)
        #pragma unroll
        for (int g = 0; g < 4; ++g)
          accd[i][g] += (double)acc[i][g];
      __syncthreads();
    }
  }

  // LSTM elementwise (torch gate order i,f,g,o); bias folded in fp64, one rounding
  const int hu = hu0 + th;
  const double bi = (double)bias[hu], bf_ = (double)bias[512 + hu];
  const double bg = (double)bias[1024 + hu], bo = (double)bias[1536 + hu];
  #pragma unroll
  for (int i = 0; i < 4; ++i) {
    const int b = b0 + tb * 4 + i;
    float ig = sigf((float)(accd[i][0] + bi));
    float fg = sigf((float)(accd[i][1] + bf_));
    float gg = tanhf((float)(accd[i][2] + bg));
    float og = sigf((float)(accd[i][3] + bo));
    float c  = fg * Cio[(size_t)b * 512 + hu] + ig * gg;
    Cio[(size_t)b * 512 + hu]  = c;
    Hout[(size_t)b * 512 + hu] = og * tanhf(c);
  }
}

// ---------------- generic out = A @ W.T + bias (for q; output-only path, fp32 ok) ----------------
__global__ __launch_bounds__(256) void gemm_bias_kernel(
    const float* __restrict__ A, const float* __restrict__ W,
    const float* __restrict__ bias, float* __restrict__ outp, int K, int N)
{
  __shared__ float As[16][64];
  __shared__ float Ws[16][64];
  const int t = threadIdx.x;
  const int tb = t >> 4, th = t & 15;
  const int b0 = blockIdx.x * 64, n0 = blockIdx.y * 64;
  const int nl = t >> 2, kk4 = (t & 3) * 4;
  float acc[4][4] = {{0.f}};
  const float* Arow = A + (size_t)(b0 + nl) * K + kk4;
  const float* Wr   = W + (size_t)(n0 + nl) * K + kk4;
  for (int k0 = 0; k0 < K; k0 += 16) {
    float4 av = *(const float4*)(Arow + k0);
    float4 wv = *(const float4*)(Wr + k0);
    As[kk4 + 0][nl] = av.x; As[kk4 + 1][nl] = av.y; As[kk4 + 2][nl] = av.z; As[kk4 + 3][nl] = av.w;
    Ws[kk4 + 0][nl] = wv.x; Ws[kk4 + 1][nl] = wv.y; Ws[kk4 + 2][nl] = wv.z; Ws[kk4 + 3][nl] = wv.w;
    __syncthreads();
    #pragma unroll
    for (int kk = 0; kk < 16; ++kk) {
      float4 a = *(const float4*)&As[kk][tb * 4];
      float4 w = *(const float4*)&Ws[kk][th * 4];
      acc[0][0] += a.x * w.x; acc[0][1] += a.x * w.y; acc[0][2] += a.x * w.z; acc[0][3] += a.x * w.w;
      acc[1][0] += a.y * w.x; acc[1][1] += a.y * w.y; acc[1][2] += a.y * w.z; acc[1][3] += a.y * w.w;
      acc[2][0] += a.z * w.x; acc[2][1] += a.z * w.y; acc[2][2] += a.z * w.z; acc[2][3] += a.z * w.w;
      acc[3][0] += a.w * w.x; acc[3][1] += a.w * w.y; acc[3][2] += a.w * w.z; acc[3][3] += a.w * w.w;
    }
    __syncthreads();
  }
  #pragma unroll
  for (int i = 0; i < 4; ++i) {
    int bb = b0 + tb * 4 + i;
    int n  = n0 + th * 4;
    float4 o;
    o.x = acc[i][0] + bias[n + 0];
    o.y = acc[i][1] + bias[n + 1];
    o.z = acc[i][2] + bias[n + 2];
    o.w = acc[i][3] + bias[n + 3];
    *(float4*)&outp[(size_t)bb * N + n] = o;
  }
}

// ---------------- enc29[b][t][:] = h1[b] @ Wfc.T + bfc ----------------
__global__ void enc29_kernel(const float* __restrict__ h1,
                             const float* __restrict__ Wfc,
                             const float* __restrict__ bfc,
                             float* __restrict__ e29, int t) {
  int b = blockIdx.x * blockDim.y + threadIdx.y;
  int v = threadIdx.x;
  if (v >= 29) return;
  const float4* hr = (const float4*)(h1 + (size_t)b * 512);
  const float4* wr = (const float4*)(Wfc + (size_t)v * 512);
  float acc = 0.f;
  #pragma unroll 4
  for (int k = 0; k < 128; ++k) {
    float4 a = hr[k], w = wr[k];
    acc += a.x * w.x + a.y * w.y + a.z * w.z + a.w * w.w;
  }
  e29[(size_t)b * 3712 + (size_t)t * 29 + v] = acc + bfc[v];
}

// ---------------- fused attention + logits + argmax + next-token, one block per b ----------------
// scores = enc29 . (q@Wv) + q.bv ; ao = (aw@enc29)@Wv.T + bv  (exact factorization, sum(aw)=1)
__global__ __launch_bounds__(256) void attn_kernel(
    const float* __restrict__ q, const float* __restrict__ h1,
    const float* __restrict__ enc29,
    const float* __restrict__ Wv, const float* __restrict__ bv,
    const float* __restrict__ Wfc1, const float* __restrict__ bfc1,
    const int* __restrict__ target, const int* __restrict__ tfm,
    int* __restrict__ tok, float* __restrict__ out_logits,
    float* __restrict__ out_attn, int t)
{
  const int b   = blockIdx.x;
  const int tid = threadIdx.x;
  __shared__ float qs[512];
  __shared__ float aos[512];
  __shared__ float aws[128];
  __shared__ float qvs[29];
  __shared__ float ctxs[29];
  __shared__ float red[256];
  __shared__ int   redi[256];

  qs[tid]       = q[(size_t)b * 512 + tid];
  qs[tid + 256] = q[(size_t)b * 512 + 256 + tid];
  __syncthreads();

  const int v = tid >> 3;
  const int j = tid & 7;
  if (v < 29) {  // qv[v] = sum_k q[k] * Wv[k][v], 8 threads per v
    float p = 0.f;
    for (int k = j * 64; k < j * 64 + 64; ++k) p += qs[k] * Wv[(size_t)k * 29 + v];
    p += __shfl_down(p, 4, 8);
    p += __shfl_down(p, 2, 8);
    p += __shfl_down(p, 1, 8);
    if (j == 0) qvs[v] = p;
  }
  // qbv = q . bv
  red[tid] = qs[tid] * bv[tid] + qs[tid + 256] * bv[tid + 256];
  __syncthreads();
  for (int off = 128; off > 0; off >>= 1) {
    if (tid < off) red[tid] += red[tid + off];
    __syncthreads();
  }
  const float qbv = red[0];
  __syncthreads();

  if (tid < 128) {  // scores
    const float* row = enc29 + (size_t)b * 3712 + (size_t)tid * 29;
    float s = qbv;
    #pragma unroll
    for (int vv = 0; vv < 29; ++vv) s += row[vv] * qvs[vv];
    aws[tid] = s;
  }
  __syncthreads();
  // softmax over 128
  red[tid] = (tid < 128) ? aws[tid] : -3.4e38f;
  __syncthreads();
  for (int off = 128; off > 0; off >>= 1) {
    if (tid < off) red[tid] = fmaxf(red[tid], red[tid + off]);
    __syncthreads();
  }
  const float m = red[0];
  __syncthreads();
  float e = 0.f;
  if (tid < 128) e = expf(aws[tid] - m);
  red[tid] = e;
  __syncthreads();
  for (int off = 128; off > 0; off >>= 1) {
    if (tid < off) red[tid] += red[tid + off];
    __syncthreads();
  }
  const float inv = 1.0f / red[0];
  __syncthreads();
  if (tid < 128) aws[tid] = e * inv;
  __syncthreads();

  if (v < 29) {  // ctx[v] = sum_s aw[s] * enc29[b][s][v]
    float p = 0.f;
    for (int s = j * 16; s < j * 16 + 16; ++s)
      p += aws[s] * enc29[(size_t)b * 3712 + (size_t)s * 29 + v];
    p += __shfl_down(p, 4, 8);
    p += __shfl_down(p, 2, 8);
    p += __shfl_down(p, 1, 8);
    if (j == 0) ctxs[v] = p;
  }
  __syncthreads();
  // ao[h] = ctx @ Wv.T + bv
  #pragma unroll
  for (int h = tid; h < 512; h += 256) {
    const float* wr = Wv + (size_t)h * 29;
    float s = bv[h];
    #pragma unroll
    for (int vv = 0; vv < 29; ++vv) s += ctxs[vv] * wr[vv];
    aos[h] = s;
  }
  __syncthreads();
  qs[tid]       = h1[(size_t)b * 512 + tid];
  qs[tid + 256] = h1[(size_t)b * 512 + 256 + tid];
  __syncthreads();
  if (v < 29) {  // logits = [h1, ao] @ Wfc1.T + bfc1
    const float* wr = Wfc1 + (size_t)v * 1024;
    float p = 0.f;
    for (int k = j * 64; k < j * 64 + 64; ++k) p += qs[k] * wr[k] + aos[k] * wr[512 + k];
    p += __shfl_down(p, 4, 8);
    p += __shfl_down(p, 2, 8);
    p += __shfl_down(p, 1, 8);
    if (j == 0) out_logits[(size_t)b * 1856 + (size_t)t * 29 + v] = p + bfc1[v];
  }
  // argmax over h1 (first-index tie-break), clipped to 28 by take(mode='clip')
  float bval = qs[tid]; int bidx = tid;
  float ov = qs[tid + 256];
  if (ov > bval) { bval = ov; bidx = tid + 256; }
  red[tid] = bval; redi[tid] = bidx;
  __syncthreads();
  for (int off = 128; off > 0; off >>= 1) {
    if (tid < off) {
      float o2 = red[tid + off]; int i2 = redi[tid + off];
      if (o2 > red[tid] || (o2 == red[tid] && i2 < redi[tid])) { red[tid] = o2; redi[tid] = i2; }
    }
    __syncthreads();
  }
  if (tid == 0) {
    int am = redi[0] > 28 ? 28 : redi[0];
    tok[b] = tfm[t] ? target[(size_t)b * 64 + t] : am;
  }
  if (t == 63 && tid < 128) out_attn[(size_t)b * 128 + tid] = aws[tid];
}

extern "C" void kernel_launch(void* const* d_in, const int* in_sizes, int n_in,
                              void* d_out, int out_size, void* d_ws, size_t ws_size,
                              hipStream_t stream) {
  (void)in_sizes; (void)n_in; (void)out_size; (void)ws_size;
  const float* x      = (const float*)d_in[0];
  const int*   target = (const int*)d_in[1];
  const float* e0_Wih = (const float*)d_in[2];
  const float* e0_Whh = (const float*)d_in[3];
  const float* e0_b   = (const float*)d_in[4];
  const float* e1_Wih = (const float*)d_in[5];
  const float* e1_Whh = (const float*)d_in[6];
  const float* e1_b   = (const float*)d_in[7];
  const float* d0_Wih = (const float*)d_in[8];
  const float* d0_Whh = (const float*)d_in[9];
  const float* d0_b   = (const float*)d_in[10];
  const float* d1_Wih = (const float*)d_in[11];
  const float* d1_Whh = (const float*)d_in[12];
  const float* d1_b   = (const float*)d_in[13];
  const float* emb    = (const float*)d_in[14];
  const float* Wq     = (const float*)d_in[15];
  const float* bq     = (const float*)d_in[16];
  const float* Wv     = (const float*)d_in[17];
  const float* bv     = (const float*)d_in[18];
  const float* Wfc    = (const float*)d_in[19];
  const float* bfc    = (const float*)d_in[20];
  const float* Wfc1   = (const float*)d_in[21];
  const float* bfc1   = (const float*)d_in[22];
  float* out = (float*)d_out;
  float* ws  = (float*)d_ws;

  const size_t NBH = 512 * 512;  // 262144
  // ws layout (floats): h[0][0] h[0][1] h[1][0] h[1][1] c0 c1 | enc29 | q | embW | tok | tfm
  float* h[2][2] = {{ws, ws + NBH}, {ws + 2 * NBH, ws + 3 * NBH}};
  float* c0   = ws + 4 * NBH;
  float* c1   = ws + 5 * NBH;
  float* e29  = ws + 6 * NBH;                 // 512*128*29 = 1900544
  float* qbuf = e29 + (size_t)512 * 128 * 29;
  float* embW = qbuf + NBH;                   // 29*2048
  int*   tok  = (int*)(embW + 29 * 2048);
  int*   tfm  = tok + 512;

  hipMemsetAsync(d_ws, 0, 6 * NBH * sizeof(float), stream);  // zero h ping-pongs + c
  hipLaunchKernelGGL(init_kernel, dim3(1), dim3(512), 0, stream, tok, tfm);
  hipLaunchKernelGGL(embw_kernel, dim3(29, 8), dim3(256), 0, stream, emb, d0_Wih, embW);

  dim3 cgrid(8, 32), cblk(256);
  // ---- encoder: 128 steps, layers interleaved per step ----
  for (int t = 0; t < 128; ++t) {
    int rp = t & 1, wp = rp ^ 1;
    hipLaunchKernelGGL(cell_kernel, cgrid, cblk, 0, stream,
                       x + t * 2, 256, (const int*)nullptr, (const float*)nullptr,
                       h[0][rp], c0, h[0][wp], e0_Wih, e0_Whh, e0_b, 0);
    hipLaunchKernelGGL(cell_kernel, cgrid, cblk, 0, stream,
                       h[0][wp], 512, (const int*)nullptr, (const float*)nullptr,
                       h[1][rp], c1, h[1][wp], e1_Wih, e1_Whh, e1_b, 1);
    hipLaunchKernelGGL(enc29_kernel, dim3(64), dim3(32, 8), 0, stream,
                       h[1][wp], Wfc, bfc, e29, t);
  }
  // hn -> d_out (final states live in parity 0 after 128 steps)
  hipMemcpyAsync(out + 950272, h[0][0], NBH * sizeof(float), hipMemcpyDeviceToDevice, stream);
  hipMemcpyAsync(out + 950272 + NBH, h[1][0], NBH * sizeof(float), hipMemcpyDeviceToDevice, stream);

  // ---- decoder: 64 steps; h/c continue from encoder finals (same buffers/parity) ----
  for (int t = 0; t < 64; ++t) {
    int rp = t & 1, wp = rp ^ 1;
    hipLaunchKernelGGL(cell_kernel, cgrid, cblk, 0, stream,
                       (const float*)nullptr, 0, tok, embW,
                       h[0][rp], c0, h[0][wp], d0_Wih, d0_Whh, d0_b, 2);
    hipLaunchKernelGGL(cell_kernel, cgrid, cblk, 0, stream,
                       h[0][wp], 512, (const int*)nullptr, (const float*)nullptr,
                       h[1][rp], c1, h[1][wp], d1_Wih, d1_Whh, d1_b, 1);
    hipLaunchKernelGGL(gemm_bias_kernel, dim3(8, 8), dim3(256), 0, stream,
                       h[1][wp], Wq, bq, qbuf, 512, 512);
    hipLaunchKernelGGL(attn_kernel, dim3(512), dim3(256), 0, stream,
                       qbuf, h[1][wp], e29, Wv, bv, Wfc1, bfc1, target, tfm, tok,
                       out, out + 1474560, t);
  }
}

// Round 4
// 21347.633 us; speedup vs baseline: 1.0856x; 1.0856x over previous
//
#include <hip/hip_runtime.h>
#include <cstddef>

// Problem constants: H=512 B=512 S=128 T=64 V=29 SOS=27 TF_RATIO=0.6
// Outputs (floats, concat): vec_out (512,64,29)=950272 | hn (2,512,512)=524288 | attn_last (512,1,128)=65536

static __device__ __forceinline__ float sigf(float x) { return 1.0f / (1.0f + expf(-x)); }
static __device__ __forceinline__ unsigned rotl32(unsigned x, int r) { return (x << r) | (x >> (32 - r)); }

// ---------------- init: tok=SOS, tf_mask = jax.random.uniform(key(42),(64,)) < 0.6 ----------------
// PARTITIONABLE threefry (modern JAX default): element i -> counter words (0, i); bits = y0 ^ y1.
__global__ __launch_bounds__(512) void init_kernel(int* __restrict__ tok, int* __restrict__ tfm) {
  int t = threadIdx.x;
  if (t < 64) {
    unsigned ks[3] = {0u, 42u, 0u ^ 42u ^ 0x1BD11BDAu};
    unsigned x0 = 0u + ks[0];              // count_hi = 0
    unsigned x1 = (unsigned)t + ks[1];     // count_lo = i
    const int RA[4] = {13, 15, 26, 6};
    const int RB[4] = {17, 29, 16, 24};
    #pragma unroll
    for (int g = 0; g < 5; ++g) {
      #pragma unroll
      for (int r = 0; r < 4; ++r) {
        int rot = (g & 1) ? RB[r] : RA[r];
        x0 += x1; x1 = rotl32(x1, rot); x1 ^= x0;
      }
      x0 += ks[(g + 1) % 3];
      x1 += ks[(g + 2) % 3] + (unsigned)(g + 1);
    }
    unsigned bits = x0 ^ x1;               // fold 64->32 (partitionable)
    float u = __uint_as_float((bits >> 9) | 0x3f800000u) - 1.0f;
    tfm[t] = (u < 0.6f) ? 1 : 0;
  }
  tok[t] = 27;  // SOS
}

// ---------------- embW = emb @ dec0_Wih.T : (29 x 2048), one-off, fp64-accurate ----------------
__global__ __launch_bounds__(256) void embw_kernel(const float* __restrict__ emb,
                                                   const float* __restrict__ Wih,
                                                   float* __restrict__ embW) {
  int v = blockIdx.x;                        // 0..28
  int n = blockIdx.y * 256 + threadIdx.x;    // 0..2047
  const float4* er = (const float4*)(emb + (size_t)v * 512);
  const float4* wr = (const float4*)(Wih + (size_t)n * 512);
  double acc = 0.0;
  #pragma unroll 4
  for (int k = 0; k < 128; ++k) {
    float4 a = er[k], w = wr[k];
    acc += (double)a.x * w.x + (double)a.y * w.y + (double)a.z * w.z + (double)a.w * w.w;
  }
  embW[(size_t)v * 2048 + n] = (float)acc;
}

// ---------------- fused LSTM cell: g = X@Wih.T + Hin@Whh.T + b; LSTM update ----------------
// Block computes 64 b x 16 hu x 4 gates. mode 0: Kx=2 (enc0, xstride=256)
// mode 1: Kx=512 dense X (stride 512). mode 2: X-part = embW[tok[b]] gather (dec0).
// Software pipeline: regs for chunk cc+1 load during compute of chunk cc -> VMEM
// latency hidden under the 256-FMA phase (1 block/CU, no TLP to hide it otherwise).
// Accuracy: fp32 FMA in 32-wide K-chunks folded into fp64 (trajectory ~exact-sum,
// so decoder argmax(h1) feedback decisions match the reference).
__global__ __launch_bounds__(256) void cell_kernel(
    const float* __restrict__ X, int xstride,
    const int* __restrict__ tok, const float* __restrict__ embW,
    const float* __restrict__ Hin, float* __restrict__ Cio, float* __restrict__ Hout,
    const float* __restrict__ Wih, const float* __restrict__ Whh,
    const float* __restrict__ bias, int mode)
{
  __shared__ float As[16][64];
  __shared__ float Ws[16][64];
  const int t   = threadIdx.x;
  const int tb  = t >> 4;            // 0..15 (b group of 4)
  const int th  = t & 15;            // 0..15 (hu)
  const int b0  = blockIdx.x * 64;
  const int hu0 = blockIdx.y * 16;
  const int nl  = t >> 2;            // 0..63 staging row
  const int kk4 = (t & 3) * 4;
  const int wrow = (nl & 3) * 512 + hu0 + (nl >> 2);  // gate*512 + hu

  double accd[4][4] = {{0.0}};

  if (mode == 0) {
    #pragma unroll
    for (int i = 0; i < 4; ++i) {
      int b = b0 + tb * 4 + i;
      float xv0 = X[(size_t)b * xstride];
      float xv1 = X[(size_t)b * xstride + 1];
      #pragma unroll
      for (int g = 0; g < 4; ++g) {
        int n = g * 512 + hu0 + th;
        accd[i][g] += (double)xv0 * Wih[n * 2] + (double)xv1 * Wih[n * 2 + 1];
      }
    }
  } else if (mode == 2) {
    #pragma unroll
    for (int i = 0; i < 4; ++i) {
      int b = b0 + tb * 4 + i;
      const float* er = embW + (size_t)tok[b] * 2048;
      #pragma unroll
      for (int g = 0; g < 4; ++g)
        accd[i][g] += (double)er[g * 512 + hu0 + th];
    }
  }

  // ---- flat pipelined GEMM over 1 or 2 K-segments of 512 (all strides 512) ----
  const float* Aseg[2]; const float* Wseg[2]; int nseg = 1;
  if (mode == 1) { Aseg[0] = X; Wseg[0] = Wih; Aseg[1] = Hin; Wseg[1] = Whh; nseg = 2; }
  else           { Aseg[0] = Hin; Wseg[0] = Whh; Aseg[1] = Hin; Wseg[1] = Whh; }

  const int NC = nseg * 32;                       // 16-K chunks
  const size_t arow = (size_t)(b0 + nl) * 512 + kk4;
  const size_t wro  = (size_t)wrow * 512 + kk4;

  float4 av = *(const float4*)(Aseg[0] + arow);
  float4 wv = *(const float4*)(Wseg[0] + wro);
  float acc[4][4] = {{0.f}};

  for (int cc = 0; cc < NC; ++cc) {
    As[kk4 + 0][nl] = av.x; As[kk4 + 1][nl] = av.y; As[kk4 + 2][nl] = av.z; As[kk4 + 3][nl] = av.w;
    Ws[kk4 + 0][nl] = wv.x; Ws[kk4 + 1][nl] = wv.y; Ws[kk4 + 2][nl] = wv.z; Ws[kk4 + 3][nl] = wv.w;
    __syncthreads();
    if (cc + 1 < NC) {  // issue next-chunk loads; latency hides under compute below
      int seg = (cc + 1) >> 5;
      int kof = ((cc + 1) & 31) * 16;
      av = *(const float4*)(Aseg[seg] + arow + kof);
      wv = *(const float4*)(Wseg[seg] + wro + kof);
    }
    #pragma unroll
    for (int kk = 0; kk < 16; ++kk) {
      float4 a = *(const float4*)&As[kk][tb * 4];
      float4 w = *(const float4*)&Ws[kk][th * 4];
      acc[0][0] += a.x * w.x; acc[0][1] += a.x * w.y; acc[0][2] += a.x * w.z; acc[0][3] += a.x * w.w;
      acc[1][0] += a.y * w.x; acc[1][1] += a.y * w.y; acc[1][2] += a.y * w.z; acc[1][3] += a.y * w.w;
      acc[2][0] += a.z * w.x; acc[2][1] += a.z * w.y; acc[2][2] += a.z * w.z; acc[2][3] += a.z * w.w;
      acc[3][0] += a.w * w.x; acc[3][1] += a.w * w.y; acc[3][2] += a.w * w.z; acc[3][3] += a.w * w.w;
    }
    if (cc & 1) {  // fold every 32 K (error ~2^-24-level; halves f64 traffic)
      #pragma unroll
      for (int i = 0; i < 4; ++i)
        #pragma unroll
        for (int g = 0; g < 4; ++g) {
          accd[i][g] += (double)acc[i][g];
          acc[i][g] = 0.f;
        }
    }
    __syncthreads();
  }

  // LSTM elementwise (torch gate order i,f,g,o); bias folded in fp64, one rounding
  const int hu = hu0 + th;
  const double bi = (double)bias[hu], bf_ = (double)bias[512 + hu];
  const double bg = (double)bias[1024 + hu], bo = (double)bias[1536 + hu];
  #pragma unroll
  for (int i = 0; i < 4; ++i) {
    const int b = b0 + tb * 4 + i;
    float ig = sigf((float)(accd[i][0] + bi));
    float fg = sigf((float)(accd[i][1] + bf_));
    float gg = tanhf((float)(accd[i][2] + bg));
    float og = sigf((float)(accd[i][3] + bo));
    float c  = fg * Cio[(size_t)b * 512 + hu] + ig * gg;
    Cio[(size_t)b * 512 + hu]  = c;
    Hout[(size_t)b * 512 + hu] = og * tanhf(c);
  }
}

// ---------------- generic out = A @ W.T + bias (for q; output-only path, fp32 ok) ----------------
__global__ __launch_bounds__(256) void gemm_bias_kernel(
    const float* __restrict__ A, const float* __restrict__ W,
    const float* __restrict__ bias, float* __restrict__ outp, int K, int N)
{
  __shared__ float As[16][64];
  __shared__ float Ws[16][64];
  const int t = threadIdx.x;
  const int tb = t >> 4, th = t & 15;
  const int b0 = blockIdx.x * 64, n0 = blockIdx.y * 64;
  const int nl = t >> 2, kk4 = (t & 3) * 4;
  float acc[4][4] = {{0.f}};
  const size_t arow = (size_t)(b0 + nl) * K + kk4;
  const size_t wro  = (size_t)(n0 + nl) * K + kk4;
  const int NC = K >> 4;
  float4 av = *(const float4*)(A + arow);
  float4 wv = *(const float4*)(W + wro);
  for (int cc = 0; cc < NC; ++cc) {
    As[kk4 + 0][nl] = av.x; As[kk4 + 1][nl] = av.y; As[kk4 + 2][nl] = av.z; As[kk4 + 3][nl] = av.w;
    Ws[kk4 + 0][nl] = wv.x; Ws[kk4 + 1][nl] = wv.y; Ws[kk4 + 2][nl] = wv.z; Ws[kk4 + 3][nl] = wv.w;
    __syncthreads();
    if (cc + 1 < NC) {
      int kof = (cc + 1) * 16;
      av = *(const float4*)(A + arow + kof);
      wv = *(const float4*)(W + wro + kof);
    }
    #pragma unroll
    for (int kk = 0; kk < 16; ++kk) {
      float4 a = *(const float4*)&As[kk][tb * 4];
      float4 w = *(const float4*)&Ws[kk][th * 4];
      acc[0][0] += a.x * w.x; acc[0][1] += a.x * w.y; acc[0][2] += a.x * w.z; acc[0][3] += a.x * w.w;
      acc[1][0] += a.y * w.x; acc[1][1] += a.y * w.y; acc[1][2] += a.y * w.z; acc[1][3] += a.y * w.w;
      acc[2][0] += a.z * w.x; acc[2][1] += a.z * w.y; acc[2][2] += a.z * w.z; acc[2][3] += a.z * w.w;
      acc[3][0] += a.w * w.x; acc[3][1] += a.w * w.y; acc[3][2] += a.w * w.z; acc[3][3] += a.w * w.w;
    }
    __syncthreads();
  }
  #pragma unroll
  for (int i = 0; i < 4; ++i) {
    int bb = b0 + tb * 4 + i;
    int n  = n0 + th * 4;
    float4 o;
    o.x = acc[i][0] + bias[n + 0];
    o.y = acc[i][1] + bias[n + 1];
    o.z = acc[i][2] + bias[n + 2];
    o.w = acc[i][3] + bias[n + 3];
    *(float4*)&outp[(size_t)bb * N + n] = o;
  }
}

// ---------------- enc29[b][t][:] = h1[b] @ Wfc.T + bfc ----------------
__global__ void enc29_kernel(const float* __restrict__ h1,
                             const float* __restrict__ Wfc,
                             const float* __restrict__ bfc,
                             float* __restrict__ e29, int t) {
  int b = blockIdx.x * blockDim.y + threadIdx.y;
  int v = threadIdx.x;
  if (v >= 29) return;
  const float4* hr = (const float4*)(h1 + (size_t)b * 512);
  const float4* wr = (const float4*)(Wfc + (size_t)v * 512);
  float acc = 0.f;
  #pragma unroll 4
  for (int k = 0; k < 128; ++k) {
    float4 a = hr[k], w = wr[k];
    acc += a.x * w.x + a.y * w.y + a.z * w.z + a.w * w.w;
  }
  e29[(size_t)b * 3712 + (size_t)t * 29 + v] = acc + bfc[v];
}

// ---------------- fused attention + logits + argmax + next-token, one block per b ----------------
// scores = enc29 . (q@Wv) + q.bv ; ao = (aw@enc29)@Wv.T + bv  (exact factorization, sum(aw)=1)
__global__ __launch_bounds__(256) void attn_kernel(
    const float* __restrict__ q, const float* __restrict__ h1,
    const float* __restrict__ enc29,
    const float* __restrict__ Wv, const float* __restrict__ bv,
    const float* __restrict__ Wfc1, const float* __restrict__ bfc1,
    const int* __restrict__ target, const int* __restrict__ tfm,
    int* __restrict__ tok, float* __restrict__ out_logits,
    float* __restrict__ out_attn, int t)
{
  const int b   = blockIdx.x;
  const int tid = threadIdx.x;
  __shared__ float qs[512];
  __shared__ float aos[512];
  __shared__ float aws[128];
  __shared__ float qvs[29];
  __shared__ float ctxs[29];
  __shared__ float red[256];
  __shared__ int   redi[256];

  qs[tid]       = q[(size_t)b * 512 + tid];
  qs[tid + 256] = q[(size_t)b * 512 + 256 + tid];
  __syncthreads();

  const int v = tid >> 3;
  const int j = tid & 7;
  if (v < 29) {  // qv[v] = sum_k q[k] * Wv[k][v], 8 threads per v
    float p = 0.f;
    for (int k = j * 64; k < j * 64 + 64; ++k) p += qs[k] * Wv[(size_t)k * 29 + v];
    p += __shfl_down(p, 4, 8);
    p += __shfl_down(p, 2, 8);
    p += __shfl_down(p, 1, 8);
    if (j == 0) qvs[v] = p;
  }
  // qbv = q . bv
  red[tid] = qs[tid] * bv[tid] + qs[tid + 256] * bv[tid + 256];
  __syncthreads();
  for (int off = 128; off > 0; off >>= 1) {
    if (tid < off) red[tid] += red[tid + off];
    __syncthreads();
  }
  const float qbv = red[0];
  __syncthreads();

  if (tid < 128) {  // scores
    const float* row = enc29 + (size_t)b * 3712 + (size_t)tid * 29;
    float s = qbv;
    #pragma unroll
    for (int vv = 0; vv < 29; ++vv) s += row[vv] * qvs[vv];
    aws[tid] = s;
  }
  __syncthreads();
  // softmax over 128
  red[tid] = (tid < 128) ? aws[tid] : -3.4e38f;
  __syncthreads();
  for (int off = 128; off > 0; off >>= 1) {
    if (tid < off) red[tid] = fmaxf(red[tid], red[tid + off]);
    __syncthreads();
  }
  const float m = red[0];
  __syncthreads();
  float e = 0.f;
  if (tid < 128) e = expf(aws[tid] - m);
  red[tid] = e;
  __syncthreads();
  for (int off = 128; off > 0; off >>= 1) {
    if (tid < off) red[tid] += red[tid + off];
    __syncthreads();
  }
  const float inv = 1.0f / red[0];
  __syncthreads();
  if (tid < 128) aws[tid] = e * inv;
  __syncthreads();

  if (v < 29) {  // ctx[v] = sum_s aw[s] * enc29[b][s][v]
    float p = 0.f;
    for (int s = j * 16; s < j * 16 + 16; ++s)
      p += aws[s] * enc29[(size_t)b * 3712 + (size_t)s * 29 + v];
    p += __shfl_down(p, 4, 8);
    p += __shfl_down(p, 2, 8);
    p += __shfl_down(p, 1, 8);
    if (j == 0) ctxs[v] = p;
  }
  __syncthreads();
  // ao[h] = ctx @ Wv.T + bv
  #pragma unroll
  for (int h = tid; h < 512; h += 256) {
    const float* wr = Wv + (size_t)h * 29;
    float s = bv[h];
    #pragma unroll
    for (int vv = 0; vv < 29; ++vv) s += ctxs[vv] * wr[vv];
    aos[h] = s;
  }
  __syncthreads();
  qs[tid]       = h1[(size_t)b * 512 + tid];
  qs[tid + 256] = h1[(size_t)b * 512 + 256 + tid];
  __syncthreads();
  if (v < 29) {  // logits = [h1, ao] @ Wfc1.T + bfc1
    const float* wr = Wfc1 + (size_t)v * 1024;
    float p = 0.f;
    for (int k = j * 64; k < j * 64 + 64; ++k) p += qs[k] * wr[k] + aos[k] * wr[512 + k];
    p += __shfl_down(p, 4, 8);
    p += __shfl_down(p, 2, 8);
    p += __shfl_down(p, 1, 8);
    if (j == 0) out_logits[(size_t)b * 1856 + (size_t)t * 29 + v] = p + bfc1[v];
  }
  // argmax over h1 (first-index tie-break), clipped to 28 by take(mode='clip')
  float bval = qs[tid]; int bidx = tid;
  float ov = qs[tid + 256];
  if (ov > bval) { bval = ov; bidx = tid + 256; }
  red[tid] = bval; redi[tid] = bidx;
  __syncthreads();
  for (int off = 128; off > 0; off >>= 1) {
    if (tid < off) {
      float o2 = red[tid + off]; int i2 = redi[tid + off];
      if (o2 > red[tid] || (o2 == red[tid] && i2 < redi[tid])) { red[tid] = o2; redi[tid] = i2; }
    }
    __syncthreads();
  }
  if (tid == 0) {
    int am = redi[0] > 28 ? 28 : redi[0];
    tok[b] = tfm[t] ? target[(size_t)b * 64 + t] : am;
  }
  if (t == 63 && tid < 128) out_attn[(size_t)b * 128 + tid] = aws[tid];
}

extern "C" void kernel_launch(void* const* d_in, const int* in_sizes, int n_in,
                              void* d_out, int out_size, void* d_ws, size_t ws_size,
                              hipStream_t stream) {
  (void)in_sizes; (void)n_in; (void)out_size; (void)ws_size;
  const float* x      = (const float*)d_in[0];
  const int*   target = (const int*)d_in[1];
  const float* e0_Wih = (const float*)d_in[2];
  const float* e0_Whh = (const float*)d_in[3];
  const float* e0_b   = (const float*)d_in[4];
  const float* e1_Wih = (const float*)d_in[5];
  const float* e1_Whh = (const float*)d_in[6];
  const float* e1_b   = (const float*)d_in[7];
  const float* d0_Wih = (const float*)d_in[8];
  const float* d0_Whh = (const float*)d_in[9];
  const float* d0_b   = (const float*)d_in[10];
  const float* d1_Wih = (const float*)d_in[11];
  const float* d1_Whh = (const float*)d_in[12];
  const float* d1_b   = (const float*)d_in[13];
  const float* emb    = (const float*)d_in[14];
  const float* Wq     = (const float*)d_in[15];
  const float* bq     = (const float*)d_in[16];
  const float* Wv     = (const float*)d_in[17];
  const float* bv     = (const float*)d_in[18];
  const float* Wfc    = (const float*)d_in[19];
  const float* bfc    = (const float*)d_in[20];
  const float* Wfc1   = (const float*)d_in[21];
  const float* bfc1   = (const float*)d_in[22];
  float* out = (float*)d_out;
  float* ws  = (float*)d_ws;

  const size_t NBH = 512 * 512;  // 262144
  // ws layout (floats): h[0][0] h[0][1] h[1][0] h[1][1] c0 c1 | enc29 | q | embW | tok | tfm
  float* h[2][2] = {{ws, ws + NBH}, {ws + 2 * NBH, ws + 3 * NBH}};
  float* c0   = ws + 4 * NBH;
  float* c1   = ws + 5 * NBH;
  float* e29  = ws + 6 * NBH;                 // 512*128*29 = 1900544
  float* qbuf = e29 + (size_t)512 * 128 * 29;
  float* embW = qbuf + NBH;                   // 29*2048
  int*   tok  = (int*)(embW + 29 * 2048);
  int*   tfm  = tok + 512;

  hipMemsetAsync(d_ws, 0, 6 * NBH * sizeof(float), stream);  // zero h ping-pongs + c
  hipLaunchKernelGGL(init_kernel, dim3(1), dim3(512), 0, stream, tok, tfm);
  hipLaunchKernelGGL(embw_kernel, dim3(29, 8), dim3(256), 0, stream, emb, d0_Wih, embW);

  dim3 cgrid(8, 32), cblk(256);
  // ---- encoder: 128 steps, layers interleaved per step ----
  for (int t = 0; t < 128; ++t) {
    int rp = t & 1, wp = rp ^ 1;
    hipLaunchKernelGGL(cell_kernel, cgrid, cblk, 0, stream,
                       x + t * 2, 256, (const int*)nullptr, (const float*)nullptr,
                       h[0][rp], c0, h[0][wp], e0_Wih, e0_Whh, e0_b, 0);
    hipLaunchKernelGGL(cell_kernel, cgrid, cblk, 0, stream,
                       h[0][wp], 512, (const int*)nullptr, (const float*)nullptr,
                       h[1][rp], c1, h[1][wp], e1_Wih, e1_Whh, e1_b, 1);
    hipLaunchKernelGGL(enc29_kernel, dim3(64), dim3(32, 8), 0, stream,
                       h[1][wp], Wfc, bfc, e29, t);
  }
  // hn -> d_out (final states live in parity 0 after 128 steps)
  hipMemcpyAsync(out + 950272, h[0][0], NBH * sizeof(float), hipMemcpyDeviceToDevice, stream);
  hipMemcpyAsync(out + 950272 + NBH, h[1][0], NBH * sizeof(float), hipMemcpyDeviceToDevice, stream);

  // ---- decoder: 64 steps; h/c continue from encoder finals (same buffers/parity) ----
  for (int t = 0; t < 64; ++t) {
    int rp = t & 1, wp = rp ^ 1;
    hipLaunchKernelGGL(cell_kernel, cgrid, cblk, 0, stream,
                       (const float*)nullptr, 0, tok, embW,
                       h[0][rp], c0, h[0][wp], d0_Wih, d0_Whh, d0_b, 2);
    hipLaunchKernelGGL(cell_kernel, cgrid, cblk, 0, stream,
                       h[0][wp], 512, (const int*)nullptr, (const float*)nullptr,
                       h[1][rp], c1, h[1][wp], d1_Wih, d1_Whh, d1_b, 1);
    hipLaunchKernelGGL(gemm_bias_kernel, dim3(8, 8), dim3(256), 0, stream,
                       h[1][wp], Wq, bq, qbuf, 512, 512);
    hipLaunchKernelGGL(attn_kernel, dim3(512), dim3(256), 0, stream,
                       qbuf, h[1][wp], e29, Wv, bv, Wfc1, bfc1, target, tfm, tok,
                       out, out + 1474560, t);
  }
}